// Round 3
// baseline (382.480 us; speedup 1.0000x reference)
//
#include <hip/hip_runtime.h>
#include <math.h>

// Problem constants: NE=1e6, NR=1000, D=32, B=2^20, CURV=1
#define NR_ 1000
#define D_ 32
#define HALF_ 16
#define EMB_DIM 33          // entity row: [x0, spatial(32)] -> 132 B, 4B-aligned
#define TAB_STRIDE 68       // precomputed relation row (272 B, 16B-aligned)

// ---------------------------------------------------------------------------
// Kernel 1: per-relation precompute (1000 rows, trivial).
//   [0:16) cos(rot)  [16:32) sin(rot)  [32:64) (sinh(vn)/vn)*0.1*trans
//   [64] cosh(rap0) [65] sinh(rap0) [66] cosh(vn) [67] pad
// ---------------------------------------------------------------------------
__global__ __launch_bounds__(256) void rel_precompute_kernel(
    const float* __restrict__ boost_w, const float* __restrict__ rot_w,
    const float* __restrict__ trans_w, float* __restrict__ tab) {
  int r = blockIdx.x * blockDim.x + threadIdx.x;
  if (r >= NR_) return;
  const float* ro = rot_w   + (size_t)r * D_;
  const float* tr = trans_w + (size_t)r * D_;
  float* o = tab + (size_t)r * TAB_STRIDE;
  #pragma unroll
  for (int j = 0; j < HALF_; ++j) {
    float th = ro[j];
    o[j]         = cosf(th);
    o[HALF_ + j] = sinf(th);
  }
  float s2 = 0.f;
  #pragma unroll
  for (int j = 0; j < D_; ++j) { float v = tr[j]; s2 = fmaf(v, v, s2); }
  float vn  = sqrtf(fmaxf(0.01f * s2, 1e-6f));
  float k   = sinhf(vn) / vn * 0.1f;
  #pragma unroll
  for (int j = 0; j < D_; ++j) o[2 * HALF_ + j] = k * tr[j];
  float rap = fminf(fmaxf(boost_w[(size_t)r * D_], -2.f), 2.f);
  o[64] = coshf(rap);
  o[65] = sinhf(rap);
  o[66] = coshf(vn);
  o[67] = 0.f;
}

// ---------------------------------------------------------------------------
// Kernel 2: wave-synchronous scoring. Block=256 (4 waves), each wave owns 64
// elements and its own 8 KB LDS slice -> NO __syncthreads anywhere (per-wave
// DS ops are in program order; compiler inserts lgkmcnt waits). 32 KB/block
// -> 5 blocks/CU = 20 waves/CU.
//
// LDS layout (per wave, 64 rows x 32 spatial floats), rotation-swizzled:
//   phys(e, j) = e*32 + ((j + e) & 31)
// Write pass (instr k): lanes 0-31 -> row e=2k, lanes 32-63 -> row e=2k+1;
// banks (jj+e)&31 -> every bank hit exactly twice = free (m136).
// Read pass (instr j): lane l reads phys(l, j), bank (j+l)&31 -> 2-way = free.
// x0 / t0 (time components) are loaded per-lane directly; their cache lines
// are touched by the staging gathers anyway.
// ---------------------------------------------------------------------------
__global__ __launch_bounds__(256, 5) void lorentz_ws_kernel(
    const int* __restrict__ heads, const int* __restrict__ rels,
    const int* __restrict__ tails, const float* __restrict__ emb,
    const float* __restrict__ bias, const float* __restrict__ tab,
    float* __restrict__ out, int n) {
  __shared__ float buf[4][2048];   // 32768 B exactly -> 5 blocks/CU

  const int lane = threadIdx.x & 63;
  const int w    = threadIdx.x >> 6;
  const int gid  = blockIdx.x * 256 + threadIdx.x;
  const int i    = (gid < n) ? gid : (n - 1);   // clamp: all lanes stay active

  const int hd = heads[i];
  const int rl = rels[i];
  const int tl = tails[i];

  const float x0   = emb[(size_t)hd * EMB_DIM];   // head time component
  const float t0   = emb[(size_t)tl * EMB_DIM];   // tail time component
  const float bsum = bias[hd] + bias[tl];
  const float4* __restrict__ T =
      reinterpret_cast<const float4*>(tab + (size_t)rl * TAB_STRIDE);

  float* __restrict__ rb = buf[w];
  const int half = lane >> 5;    // 0 | 1
  const int jj   = lane & 31;

  // ---- Stage head spatial rows: 32 coalesced-gather loads, then 32 writes.
  // Row index for instr k is half-wave-uniform (e = 2k + half): fetch both
  // candidates with v_readlane (scalar pipe) + cndmask — no LDS-pipe cost.
  float hv[32];
  #pragma unroll
  for (int k = 0; k < 32; ++k) {
    int r0  = __builtin_amdgcn_readlane(hd, 2 * k);
    int r1  = __builtin_amdgcn_readlane(hd, 2 * k + 1);
    int row = half ? r1 : r0;
    hv[k] = emb[(size_t)row * EMB_DIM + 1 + jj];
  }
  #pragma unroll
  for (int k = 0; k < 32; ++k) {
    int e = 2 * k + half;
    rb[(e << 5) | ((jj + e) & 31)] = hv[k];
  }

  // ---- Prefetch tail spatial rows into registers NOW: their HBM latency
  // hides under the head LDS round-trip + rotation/boost math below.
  float tv[32];
  #pragma unroll
  for (int k = 0; k < 32; ++k) {
    int r0  = __builtin_amdgcn_readlane(tl, 2 * k);
    int r1  = __builtin_amdgcn_readlane(tl, 2 * k + 1);
    int row = half ? r1 : r0;
    tv[k] = emb[(size_t)row * EMB_DIM + 1 + jj];
  }

  // ---- Head compute: rotation (fused with LDS reads), boost, translation.
  float r[D_];
  #pragma unroll
  for (int q = 0; q < 4; ++q) {
    float4 cv = T[q];
    float4 sv = T[4 + q];
    float cj[4] = {cv.x, cv.y, cv.z, cv.w};
    float sj[4] = {sv.x, sv.y, sv.z, sv.w};
    #pragma unroll
    for (int m = 0; m < 4; ++m) {
      int j = 4 * q + m;
      float a = rb[(lane << 5) | ((j + lane) & 31)];
      float b = rb[(lane << 5) | ((j + 16 + lane) & 31)];
      r[j]         = cj[m] * a - sj[m] * b;
      r[HALF_ + j] = sj[m] * a + cj[m] * b;
    }
  }
  float4 hv4 = T[16];              // {cosh(rap), sinh(rap), cosh(vn), -}
  r[0] = fmaf(x0, hv4.y, r[0] * hv4.x);
  const float cvn = hv4.z;

  float rs[D_];
  float n2 = 0.f;
  #pragma unroll
  for (int q = 0; q < 8; ++q) {
    float4 kv = T[8 + q];
    float kj[4] = {kv.x, kv.y, kv.z, kv.w};
    #pragma unroll
    for (int m = 0; m < 4; ++m) {
      int j = 4 * q + m;
      rs[j] = fmaf(cvn, r[j], kj[m]);
      n2 = fmaf(rs[j], rs[j], n2);
    }
  }
  const float ht0 = sqrtf(1.f + n2);

  // ---- Tail phase: write prefetched rows (same buffer; per-wave DS order
  // guarantees the head reads above already consumed the LDS), then dot.
  #pragma unroll
  for (int k = 0; k < 32; ++k) {
    int e = 2 * k + half;
    rb[(e << 5) | ((jj + e) & 31)] = tv[k];
  }
  float dot = 0.f;
  #pragma unroll
  for (int j = 0; j < D_; ++j) {
    float tj = rb[(lane << 5) | ((j + lane) & 31)];
    dot = fmaf(rs[j], tj, dot);
  }

  float neg_inner = fmaf(ht0, t0, -dot);          // -lorentz_inner
  float ic   = fmaxf(neg_inner, 1.0f + 1e-6f);
  float dist = acoshf(ic);
  if (gid < n) out[gid] = bsum - dist * dist;
}

// ---------------------------------------------------------------------------
// Fallback (ws too small for tab): fully inline scalar path.
// ---------------------------------------------------------------------------
__global__ __launch_bounds__(256) void lorentz_fallback_kernel(
    const int* __restrict__ heads, const int* __restrict__ rels,
    const int* __restrict__ tails, const float* __restrict__ emb,
    const float* __restrict__ boost_w, const float* __restrict__ rot_w,
    const float* __restrict__ trans_w, const float* __restrict__ bias,
    float* __restrict__ out, int n) {
  int i = blockIdx.x * blockDim.x + threadIdx.x;
  if (i >= n) return;
  int hd = heads[i], rl = rels[i], tl = tails[i];
  const float* hrow = emb + (size_t)hd * EMB_DIM;
  const float* trow = emb + (size_t)tl * EMB_DIM;
  const float* ro = rot_w   + (size_t)rl * D_;
  const float* tr = trans_w + (size_t)rl * D_;
  float c[HALF_], s[HALF_], kt[D_];
  #pragma unroll
  for (int j = 0; j < HALF_; ++j) { float th = ro[j]; c[j] = cosf(th); s[j] = sinf(th); }
  float s2 = 0.f;
  #pragma unroll
  for (int j = 0; j < D_; ++j) { float v = tr[j]; s2 = fmaf(v, v, s2); }
  float vn = sqrtf(fmaxf(0.01f * s2, 1e-6f));
  float cvn = coshf(vn);
  float k = sinhf(vn) / vn * 0.1f;
  #pragma unroll
  for (int j = 0; j < D_; ++j) kt[j] = k * tr[j];
  float rap = fminf(fmaxf(boost_w[(size_t)rl * D_], -2.f), 2.f);
  float c0 = coshf(rap), s0 = sinhf(rap);
  float x0 = hrow[0];
  float r[D_];
  #pragma unroll
  for (int j = 0; j < HALF_; ++j) {
    float a = hrow[1 + j], b = hrow[1 + HALF_ + j];
    r[j] = c[j] * a - s[j] * b;
    r[HALF_ + j] = s[j] * a + c[j] * b;
  }
  r[0] = fmaf(x0, s0, r[0] * c0);
  float t0 = trow[0], n2 = 0.f, dot = 0.f;
  #pragma unroll
  for (int j = 0; j < D_; ++j) {
    float rsv = fmaf(cvn, r[j], kt[j]);
    n2  = fmaf(rsv, rsv, n2);
    dot = fmaf(rsv, trow[1 + j], dot);
  }
  float ht0 = sqrtf(1.f + n2);
  float neg_inner = fmaf(ht0, t0, -dot);
  float ic = fmaxf(neg_inner, 1.0f + 1e-6f);
  float dist = acoshf(ic);
  out[i] = bias[hd] + bias[tl] - dist * dist;
}

extern "C" void kernel_launch(void* const* d_in, const int* in_sizes, int n_in,
                              void* d_out, int out_size, void* d_ws, size_t ws_size,
                              hipStream_t stream) {
  const int*   heads  = (const int*)d_in[0];
  const int*   rels   = (const int*)d_in[1];
  const int*   tails  = (const int*)d_in[2];
  const float* emb    = (const float*)d_in[3];
  const float* boostw = (const float*)d_in[4];
  const float* rotw   = (const float*)d_in[5];
  const float* transw = (const float*)d_in[6];
  const float* bias   = (const float*)d_in[7];
  float* out = (float*)d_out;
  int n = in_sizes[0];  // B = 1048576

  size_t tab_bytes = (size_t)NR_ * TAB_STRIDE * sizeof(float);
  dim3 block(256);
  dim3 grid((n + 255) / 256);

  if (ws_size >= tab_bytes) {
    float* tab = (float*)d_ws;
    rel_precompute_kernel<<<dim3((NR_ + 255) / 256), block, 0, stream>>>(
        boostw, rotw, transw, tab);
    lorentz_ws_kernel<<<grid, block, 0, stream>>>(
        heads, rels, tails, emb, bias, tab, out, n);
  } else {
    lorentz_fallback_kernel<<<grid, block, 0, stream>>>(
        heads, rels, tails, emb, boostw, rotw, transw, bias, out, n);
  }
}